// Round 7
// baseline (67.623 us; speedup 1.0000x reference)
//
#include <hip/hip_runtime.h>
#include <math.h>

#define NB 4096
#define NIN 128
#define NH 256
#define ND 32
#define NC 8
#define NK 256
#define NHS 16

// output offsets (in floats), concatenated in reference return order
#define OFF_KCHART 0
#define OFF_KCODE  4096
#define OFF_ZN     8192
#define OFF_ZTEX   (OFF_ZN + 4096*32)        // 139264
#define OFF_ROUTER (OFF_ZTEX + 4096*32)      // 270336 (float4-aligned)
#define OFF_ZGEO   (OFF_ROUTER + 4096*8)     // 303104
#define OFF_LOSS   (OFF_ZGEO + 4096*32)      // 434176
#define OFF_IND    (OFF_LOSS + 1)            // 434177 (odd -> scalar access only)
#define OFF_ZNALL  (OFF_IND + 4096*8)        // 466945 (odd -> scalar access only)
#define OFF_CBAR   (OFF_ZNALL + 4096*8*32)   // 1515521 (odd -> scalar)
#define OFF_VLOC   (OFF_CBAR + 4096*32)      // 1646593 (odd -> scalar)

__device__ __forceinline__ float gelu_exact(float x) {
    return x * (erff(x / 1.41421356237309504f) + 1.0f) * 0.5f;
}

// ---------------------------------------------------------------------------
// GEMM1: h1 = gelu(x @ W1 + b1). 32x64 tile, 2x4 micro, grid (4,128).
// B in LDS (dbuf, one barrier/tile); A streamed global->regs.
// ---------------------------------------------------------------------------
template<int K>
__global__ __launch_bounds__(256)
void gemm_bias_gelu(const float* __restrict__ A, const float* __restrict__ W,
                    const float* __restrict__ bias, float* __restrict__ out) {
    const int N = 256;
    __shared__ float sB[2][32][68];
    const int t  = threadIdx.x;
    const int n0 = blockIdx.x * 64;
    const int r0 = blockIdx.y * 32;
    const int ty = t >> 4, tx = t & 15;
    const int bk = t >> 4, bc = t & 15;

    float4 bias4 = *(const float4*)(bias + n0 + tx * 4);
    float4 pb0 = *(const float4*)(W + bk * N + n0 + bc * 4);
    float4 pb1 = *(const float4*)(W + (bk + 16) * N + n0 + bc * 4);

    const float* Ab0 = A + (r0 + ty * 2 + 0) * K;
    const float* Ab1 = A + (r0 + ty * 2 + 1) * K;
    float ac[2][4], an[2][4];
    {
        float4 c0 = *(const float4*)(Ab0 + 0), c1 = *(const float4*)(Ab1 + 0);
        ac[0][0]=c0.x; ac[0][1]=c0.y; ac[0][2]=c0.z; ac[0][3]=c0.w;
        ac[1][0]=c1.x; ac[1][1]=c1.y; ac[1][2]=c1.z; ac[1][3]=c1.w;
        float4 d0 = *(const float4*)(Ab0 + 4), d1 = *(const float4*)(Ab1 + 4);
        an[0][0]=d0.x; an[0][1]=d0.y; an[0][2]=d0.z; an[0][3]=d0.w;
        an[1][0]=d1.x; an[1][1]=d1.y; an[1][2]=d1.z; an[1][3]=d1.w;
    }

    float acc[2][4];
    #pragma unroll
    for (int i = 0; i < 2; i++)
        #pragma unroll
        for (int j = 0; j < 4; j++) acc[i][j] = 0.f;

    int buf = 0;
    for (int kk = 0; kk < K; kk += 32) {
        *(float4*)(&sB[buf][bk][bc*4])    = pb0;
        *(float4*)(&sB[buf][bk+16][bc*4]) = pb1;
        __syncthreads();
        if (kk + 32 < K) {
            pb0 = *(const float4*)(W + (kk + 32 + bk) * N + n0 + bc * 4);
            pb1 = *(const float4*)(W + (kk + 32 + bk + 16) * N + n0 + bc * 4);
        }
        #pragma unroll
        for (int c = 0; c < 8; c++) {
            int knext = kk + (c + 2) * 4;
            if (knext > K - 4) knext = K - 4;
            float4 p0 = *(const float4*)(Ab0 + knext);
            float4 p1 = *(const float4*)(Ab1 + knext);
            #pragma unroll
            for (int u = 0; u < 4; u++) {
                float4 bv = *(const float4*)(&sB[buf][c * 4 + u][tx * 4]);
                float bb[4] = {bv.x, bv.y, bv.z, bv.w};
                #pragma unroll
                for (int j = 0; j < 4; j++) {
                    acc[0][j] = fmaf(ac[0][u], bb[j], acc[0][j]);
                    acc[1][j] = fmaf(ac[1][u], bb[j], acc[1][j]);
                }
            }
            #pragma unroll
            for (int u = 0; u < 4; u++) { ac[0][u] = an[0][u]; ac[1][u] = an[1][u]; }
            an[0][0]=p0.x; an[0][1]=p0.y; an[0][2]=p0.z; an[0][3]=p0.w;
            an[1][0]=p1.x; an[1][1]=p1.y; an[1][2]=p1.z; an[1][3]=p1.w;
        }
        buf ^= 1;
    }
    float bb4[4] = {bias4.x, bias4.y, bias4.z, bias4.w};
    #pragma unroll
    for (int i = 0; i < 2; i++) {
        int row = r0 + ty * 2 + i;
        float4 o;
        float* op = (float*)&o;
        #pragma unroll
        for (int j = 0; j < 4; j++) op[j] = gelu_exact(acc[i][j] + bb4[j]);
        *(float4*)(out + row * N + n0 + tx * 4) = o;
    }
}

// ---------------------------------------------------------------------------
// GEMM2 + v-projection epilogue: feats stays in registers (never written).
// Each block (32 rows x 64 feat-cols) emits its 64-col partial of
// v = feats @ Wv into vpart[blockIdx.x][row][c] via width-16 shuffle tree.
// ---------------------------------------------------------------------------
__global__ __launch_bounds__(256)
void gemm2_vproj(const float* __restrict__ A, const float* __restrict__ W,
                 const float* __restrict__ bias, const float* __restrict__ Wv,
                 float* __restrict__ vpart) {
    const int K = 256, N = 256;
    __shared__ float sB[2][32][68];
    __shared__ float sWvT[32][68];   // [c][kp], kp = col within this block's 64
    const int t  = threadIdx.x;
    const int n0 = blockIdx.x * 64;
    const int r0 = blockIdx.y * 32;
    const int ty = t >> 4, tx = t & 15;
    const int bk = t >> 4, bc = t & 15;

    float4 bias4 = *(const float4*)(bias + n0 + tx * 4);
    float4 pb0 = *(const float4*)(W + bk * N + n0 + bc * 4);
    float4 pb1 = *(const float4*)(W + (bk + 16) * N + n0 + bc * 4);

    const float* Ab0 = A + (r0 + ty * 2 + 0) * K;
    const float* Ab1 = A + (r0 + ty * 2 + 1) * K;
    float ac[2][4], an[2][4];
    {
        float4 c0 = *(const float4*)(Ab0 + 0), c1 = *(const float4*)(Ab1 + 0);
        ac[0][0]=c0.x; ac[0][1]=c0.y; ac[0][2]=c0.z; ac[0][3]=c0.w;
        ac[1][0]=c1.x; ac[1][1]=c1.y; ac[1][2]=c1.z; ac[1][3]=c1.w;
        float4 d0 = *(const float4*)(Ab0 + 4), d1 = *(const float4*)(Ab1 + 4);
        an[0][0]=d0.x; an[0][1]=d0.y; an[0][2]=d0.z; an[0][3]=d0.w;
        an[1][0]=d1.x; an[1][1]=d1.y; an[1][2]=d1.z; an[1][3]=d1.w;
    }

    float acc[2][4];
    #pragma unroll
    for (int i = 0; i < 2; i++)
        #pragma unroll
        for (int j = 0; j < 4; j++) acc[i][j] = 0.f;

    int buf = 0;
    for (int kk = 0; kk < K; kk += 32) {
        *(float4*)(&sB[buf][bk][bc*4])    = pb0;
        *(float4*)(&sB[buf][bk+16][bc*4]) = pb1;
        __syncthreads();
        if (kk + 32 < K) {
            pb0 = *(const float4*)(W + (kk + 32 + bk) * N + n0 + bc * 4);
            pb1 = *(const float4*)(W + (kk + 32 + bk + 16) * N + n0 + bc * 4);
        }
        #pragma unroll
        for (int c = 0; c < 8; c++) {
            int knext = kk + (c + 2) * 4;
            if (knext > K - 4) knext = K - 4;
            float4 p0 = *(const float4*)(Ab0 + knext);
            float4 p1 = *(const float4*)(Ab1 + knext);
            #pragma unroll
            for (int u = 0; u < 4; u++) {
                float4 bv = *(const float4*)(&sB[buf][c * 4 + u][tx * 4]);
                float bb[4] = {bv.x, bv.y, bv.z, bv.w};
                #pragma unroll
                for (int j = 0; j < 4; j++) {
                    acc[0][j] = fmaf(ac[0][u], bb[j], acc[0][j]);
                    acc[1][j] = fmaf(ac[1][u], bb[j], acc[1][j]);
                }
            }
            #pragma unroll
            for (int u = 0; u < 4; u++) { ac[0][u] = an[0][u]; ac[1][u] = an[1][u]; }
            an[0][0]=p0.x; an[0][1]=p0.y; an[0][2]=p0.z; an[0][3]=p0.w;
            an[1][0]=p1.x; an[1][1]=p1.y; an[1][2]=p1.z; an[1][3]=p1.w;
        }
        buf ^= 1;
    }
    // gelu -> feats fragment in registers (rows r0+ty*2+{0,1}, cols n0+tx*4+{0..3})
    float f[2][4];
    {
        float bb4[4] = {bias4.x, bias4.y, bias4.z, bias4.w};
        #pragma unroll
        for (int i = 0; i < 2; i++)
            #pragma unroll
            for (int j = 0; j < 4; j++) f[i][j] = gelu_exact(acc[i][j] + bb4[j]);
    }
    // stage Wv slice transposed: sWvT[c][kp] = Wv[n0+kp][c], kp in [0,64)
    #pragma unroll
    for (int q = 0; q < 2; q++) {
        int id = t * 2 + q;           // 0..511 covers 64x32/4
        int kr = id >> 3, c4 = (id & 7) * 4;
        float4 w = *(const float4*)(Wv + (n0 + kr) * ND + c4);
        sWvT[c4+0][kr] = w.x; sWvT[c4+1][kr] = w.y;
        sWvT[c4+2][kr] = w.z; sWvT[c4+3][kr] = w.w;
    }
    __syncthreads();
    // partial v: reduce over this block's 64 cols (16 tx-lanes x 4 each)
    #pragma unroll
    for (int c = 0; c < ND; c++) {
        float4 w = *(const float4*)(&sWvT[c][tx * 4]);
        float s0 = f[0][0] * w.x; s0 = fmaf(f[0][1], w.y, s0);
        s0 = fmaf(f[0][2], w.z, s0); s0 = fmaf(f[0][3], w.w, s0);
        float s1 = f[1][0] * w.x; s1 = fmaf(f[1][1], w.y, s1);
        s1 = fmaf(f[1][2], w.z, s1); s1 = fmaf(f[1][3], w.w, s1);
        s0 += __shfl_down(s0, 8, 16); s1 += __shfl_down(s1, 8, 16);
        s0 += __shfl_down(s0, 4, 16); s1 += __shfl_down(s1, 4, 16);
        s0 += __shfl_down(s0, 2, 16); s1 += __shfl_down(s1, 2, 16);
        s0 += __shfl_down(s0, 1, 16); s1 += __shfl_down(s1, 1, 16);
        if (tx == 0) {
            vpart[blockIdx.x * (NB * ND) + (r0 + ty * 2 + 0) * ND + c] = s0;
            vpart[blockIdx.x * (NB * ND) + (r0 + ty * 2 + 1) * ND + c] = s1;
        }
    }
}

// ---------------------------------------------------------------------------
// vq_chart v2: block = 64 rows x 1 chart, grid 512.
// Prologue: v = sum(4 vpart) + bv ; scores ; softmax ; K_chart ; c_bar ;
// v_local (in sV). chart-0 blocks write router/K_chart/CBAR/VLOC/vloc_ws.
// Then: |e|^2, argmin, zn MLP, hyperbolic loss (unchanged structure).
// ---------------------------------------------------------------------------
__global__ __launch_bounds__(256)
void vq_chart(const float* __restrict__ codebook, const float* __restrict__ centers,
              const float* __restrict__ bvp, const float* __restrict__ vpart,
              const float* __restrict__ Ws1, const float* __restrict__ bs1,
              const float* __restrict__ Ws2, const float* __restrict__ bs2,
              float* __restrict__ out, float* __restrict__ vloc_ws,
              float* __restrict__ loss_partial) {
    __shared__ float sCB[NK][36];
    __shared__ float sEn2[NK];
    __shared__ float sV[64][36];
    __shared__ float sCent[NC * ND];
    __shared__ float sbv[ND];
    __shared__ float sScore[64][NC + 1];
    __shared__ float sRout[64][NC + 1];
    __shared__ float sBest[8][64];
    __shared__ int   sBidx[8][64];
    __shared__ int   sSel[64];
    __shared__ float sPscale[64];
    __shared__ float sLossArr[64];
    __shared__ float sWs1[ND][17];
    __shared__ float sWs2[NHS][33];
    __shared__ float sbs1[NHS], sbs2v[ND];
    const int t = threadIdx.x;
    const int cblk = blockIdx.x & 7;
    const int row0 = (blockIdx.x >> 3) * 64;

    // ---- staging ----
    {
        const float4* src = (const float4*)(codebook + cblk * NK * ND);
        #pragma unroll
        for (int q = 0; q < 8; q++) {
            int id = t + q * 256;
            int code = id >> 3, kq = (id & 7) * 4;
            *(float4*)(&sCB[code][kq]) = src[id];
        }
        // v = p0+p1+p2+p3 + bv
        #pragma unroll
        for (int q = 0; q < 2; q++) {
            int id = t + q * 256;          // 512 float4 = 64x32
            int rr = id >> 3, c4 = id & 7;
            const float4* p0 = (const float4*)(vpart + 0 * (NB * ND) + (row0 + rr) * ND);
            const float4* p1 = (const float4*)(vpart + 1 * (NB * ND) + (row0 + rr) * ND);
            const float4* p2 = (const float4*)(vpart + 2 * (NB * ND) + (row0 + rr) * ND);
            const float4* p3 = (const float4*)(vpart + 3 * (NB * ND) + (row0 + rr) * ND);
            float4 a = p0[c4], b = p1[c4], cc = p2[c4], d = p3[c4];
            float4 bb = ((const float4*)bvp)[c4];
            float4 v;
            v.x = a.x + b.x + cc.x + d.x + bb.x;
            v.y = a.y + b.y + cc.y + d.y + bb.y;
            v.z = a.z + b.z + cc.z + d.z + bb.z;
            v.w = a.w + b.w + cc.w + d.w + bb.w;
            *(float4*)(&sV[rr][c4 * 4]) = v;
        }
    }
    if (t < 64) ((float4*)sCent)[t] = ((const float4*)centers)[t];
    if (t >= 64 && t < 72) ((float4*)sbv)[t - 64] = ((const float4*)bvp)[t - 64];
    if (t >= 128 && t < 256) {
        int u = t - 128;
        if (u < 64) {            // not used; placeholder branch keeps staging simple
        }
    }
    if (t < 128) {
        float4 w = ((const float4*)Ws1)[t];
        int k = t >> 2, o = (t & 3) * 4;
        sWs1[k][o] = w.x; sWs1[k][o+1] = w.y; sWs1[k][o+2] = w.z; sWs1[k][o+3] = w.w;
    } else {
        int u = t - 128;
        float4 w = ((const float4*)Ws2)[u];
        int k = u >> 3, o = (u & 7) * 4;
        sWs2[k][o] = w.x; sWs2[k][o+1] = w.y; sWs2[k][o+2] = w.z; sWs2[k][o+3] = w.w;
    }
    if (t < NHS) sbs1[t] = bs1[t];
    else if (t < NHS + ND) sbs2v[t - NHS] = bs2[t - NHS];
    __syncthreads();

    // ---- scores: r = t>>2, two charts per thread ----
    {
        const int r = t >> 2, cp = t & 3;
        float4 vr[8];
        #pragma unroll
        for (int q = 0; q < 8; q++) vr[q] = *(const float4*)(&sV[r][q * 4]);
        #pragma unroll
        for (int cc = 0; cc < 2; cc++) {
            int ch = cp * 2 + cc;
            float s = 0.f;
            #pragma unroll
            for (int q = 0; q < 8; q++) {
                float4 ce = *(const float4*)(&sCent[ch * ND + q * 4]);
                s = fmaf(vr[q].x, ce.x, s);
                s = fmaf(vr[q].y, ce.y, s);
                s = fmaf(vr[q].z, ce.z, s);
                s = fmaf(vr[q].w, ce.w, s);
            }
            sScore[r][ch] = s / 5.65685424949238f;
        }
    }
    __syncthreads();
    // ---- softmax / K_chart ----
    if (t < 64) {
        const int r = t, grow = row0 + r;
        float sc[NC];
        float m = -3.4e38f; int kmax = 0;
        #pragma unroll
        for (int c = 0; c < NC; c++) {
            float s = sScore[r][c];
            sc[c] = s;
            if (s > m) { m = s; kmax = c; }
        }
        float ssum = 0.f;
        #pragma unroll
        for (int c = 0; c < NC; c++) { float e = expf(sc[c] - m); sc[c] = e; ssum += e; }
        float inv = 1.f / ssum;
        #pragma unroll
        for (int c = 0; c < NC; c++) {
            float rv = sc[c] * inv;
            sRout[r][c] = rv;
            if (cblk == 0) out[OFF_ROUTER + grow * NC + c] = rv;
        }
        if (cblk == 0) out[OFF_KCHART + grow] = (float)kmax;
    }
    __syncthreads();
    // ---- c_bar / v_local (overwrite sV) + per-code |e|^2 ----
    {
        const int r = t >> 2, q = t & 3;
        #pragma unroll
        for (int u = 0; u < 8; u++) {
            int col = q * 8 + u;
            float cb = 0.f;
            #pragma unroll
            for (int c = 0; c < NC; c++) cb = fmaf(sRout[r][c], sCent[c * ND + col], cb);
            float vl = sV[r][col] - cb;
            sV[r][col] = vl;
            if (cblk == 0) {
                out[OFF_CBAR + (row0 + r) * ND + col] = cb;
                out[OFF_VLOC + (row0 + r) * ND + col] = vl;
                vloc_ws[(row0 + r) * ND + col] = vl;
            }
        }
        float s = 0.f;
        #pragma unroll
        for (int qq = 0; qq < 8; qq++) {
            float4 e = *(const float4*)(&sCB[t][qq * 4]);
            s = fmaf(e.x, e.x, s); s = fmaf(e.y, e.y, s);
            s = fmaf(e.z, e.z, s); s = fmaf(e.w, e.w, s);
        }
        sEn2[t] = s;
    }
    __syncthreads();

    // ---- argmin ----
    const int r = t & 31, g = t >> 5;
    float vl0[ND], vl1[ND];
    #pragma unroll
    for (int q = 0; q < 8; q++) {
        float4 a = *(const float4*)(&sV[r][q * 4]);
        vl0[q*4] = a.x; vl0[q*4+1] = a.y; vl0[q*4+2] = a.z; vl0[q*4+3] = a.w;
        float4 b = *(const float4*)(&sV[r + 32][q * 4]);
        vl1[q*4] = b.x; vl1[q*4+1] = b.y; vl1[q*4+2] = b.z; vl1[q*4+3] = b.w;
    }
    float best0 = 3.4e38f, best1 = 3.4e38f;
    int bi0 = 0, bi1 = 0;
    for (int j = 0; j < 32; j++) {
        const int code = g * 32 + j;
        float dot0 = 0.f, dot1 = 0.f;
        #pragma unroll
        for (int q = 0; q < 8; q++) {
            float4 e = *(const float4*)(&sCB[code][q * 4]);
            dot0 = fmaf(vl0[q*4+0], e.x, dot0); dot1 = fmaf(vl1[q*4+0], e.x, dot1);
            dot0 = fmaf(vl0[q*4+1], e.y, dot0); dot1 = fmaf(vl1[q*4+1], e.y, dot1);
            dot0 = fmaf(vl0[q*4+2], e.z, dot0); dot1 = fmaf(vl1[q*4+2], e.z, dot1);
            dot0 = fmaf(vl0[q*4+3], e.w, dot0); dot1 = fmaf(vl1[q*4+3], e.w, dot1);
        }
        const float en2 = sEn2[code];
        float d0 = en2 - 2.f * dot0;
        float d1 = en2 - 2.f * dot1;
        if (d0 < best0) { best0 = d0; bi0 = code; }
        if (d1 < best1) { best1 = d1; bi1 = code; }
    }
    sBest[g][r] = best0;      sBidx[g][r] = bi0;
    sBest[g][r + 32] = best1; sBidx[g][r + 32] = bi1;
    __syncthreads();
    if (t < 64) {
        float bb = sBest[0][t]; int ii = sBidx[0][t];
        #pragma unroll
        for (int gg = 1; gg < 8; gg++) {
            float v = sBest[gg][t];
            if (v < bb) { bb = v; ii = sBidx[gg][t]; }
        }
        sSel[t] = ii;
        out[OFF_IND + (row0 + t) * NC + cblk] = (float)ii;
        float vn2 = 0.f;
        #pragma unroll
        for (int k = 0; k < ND; k++) { float v = sV[t][k]; vn2 = fmaf(v, v, vn2); }
        float norm = fmaxf(sqrtf(vn2), 1e-6f);
        sPscale[t] = fminf(0.99f / norm, 1.0f);
    }
    __syncthreads();

    // ---- zn MLP + loss, 4 passes of 16 rows ----
    const int i = t & 15, r16 = t >> 4;
    const float b1r = sbs1[i];
    const float bo0 = sbs2v[2*i], bo1 = sbs2v[2*i+1];
    #pragma unroll
    for (int pass = 0; pass < 4; pass++) {
        const int lrow = pass * 16 + r16;
        const int grow = row0 + lrow;
        const int sel = sSel[lrow];
        const float rc = sRout[lrow][cblk];
        const float ps = sPscale[lrow];
        float acc1 = b1r;
        #pragma unroll
        for (int k = 0; k < ND; k++) {
            float dlt = sV[lrow][k] - sCB[sel][k];
            acc1 = fmaf(dlt, sWs1[k][i], acc1);
        }
        float h = gelu_exact(acc1);
        float a0 = bo0, a1 = bo1;
        #pragma unroll
        for (int k = 0; k < NHS; k++) {
            float s1k = __shfl(h, k, 16);
            a0 = fmaf(s1k, sWs2[k][2*i],   a0);
            a1 = fmaf(s1k, sWs2[k][2*i+1], a1);
        }
        out[OFF_ZNALL + (grow * NC + cblk) * ND + 2*i]     = a0;
        out[OFF_ZNALL + (grow * NC + cblk) * ND + 2*i + 1] = a1;
        const float e0 = sCB[sel][2*i], e1 = sCB[sel][2*i+1];
        float yp0 = sV[lrow][2*i] * ps, yp1 = sV[lrow][2*i+1] * ps;
        float d0 = e0 - yp0, d1 = e1 - yp1;
        float sq = fmaf(d0, d0, d1 * d1);
        float xn = fmaf(e0, e0, e1 * e1);
        float yn = fmaf(yp0, yp0, yp1 * yp1);
        #pragma unroll
        for (int m = 1; m < 16; m <<= 1) {
            sq += __shfl_xor(sq, m, 16);
            xn += __shfl_xor(xn, m, 16);
            yn += __shfl_xor(yn, m, 16);
        }
        if (i == 0) {
            float denom = fmaxf((1.f - xn) * (1.f - yn), 1e-6f);
            float arg = fmaxf(1.f + 2.f * sq / denom, 1.f + 1e-6f);
            float dd = acoshf(arg);
            sLossArr[lrow] = dd * dd * rc;
        }
    }
    __syncthreads();
    if (t < 64) {
        float v = sLossArr[t];
        #pragma unroll
        for (int off = 32; off > 0; off >>= 1) v += __shfl_down(v, off, 64);
        if (t == 0) loss_partial[blockIdx.x] = v;
    }
}

// ---------------------------------------------------------------------------
// finalize: one col/thread, grid 512 + loss reduce in block 0.
// ---------------------------------------------------------------------------
__global__ __launch_bounds__(256)
void finalize2_kernel(const float* __restrict__ codebook, const float* __restrict__ vloc_ws,
                      float* __restrict__ out, const float* __restrict__ partials) {
    const int gid = blockIdx.x * 256 + threadIdx.x;
    const int row = gid >> 5;
    const int col = gid & 31;
    float rout[NC]; int ind[NC];
    #pragma unroll
    for (int cc = 0; cc < NC; cc++) {
        rout[cc] = out[OFF_ROUTER + row * NC + cc];
        ind[cc]  = (int)out[OFF_IND + row * NC + cc];
    }
    float zn = 0.f, zq = 0.f;
    #pragma unroll
    for (int cc = 0; cc < NC; cc++) {
        const float rcc = rout[cc];
        zn = fmaf(out[OFF_ZNALL + (row * NC + cc) * ND + col], rcc, zn);
        zq = fmaf(codebook[(cc * NK + ind[cc]) * ND + col], rcc, zq);
    }
    const float vl = vloc_ws[row * ND + col];
    const float cb = out[OFF_CBAR + row * ND + col];
    out[OFF_ZN   + row * ND + col] = zn;
    out[OFF_ZTEX + row * ND + col] = vl - zq - zn;
    out[OFF_ZGEO + row * ND + col] = cb + zq + zn;
    if (col == 0) {
        int kc = (int)out[OFF_KCHART + row];
        out[OFF_KCODE + row] = out[OFF_IND + row * NC + kc];
    }
    if (blockIdx.x == 0) {
        __shared__ float sTmp[4];
        const int t = threadIdx.x;
        float v = partials[t] + partials[t + 256];
        #pragma unroll
        for (int off = 32; off > 0; off >>= 1) v += __shfl_down(v, off, 64);
        if ((t & 63) == 0) sTmp[t >> 6] = v;
        __syncthreads();
        if (t == 0) out[OFF_LOSS] = 1.25f * (sTmp[0] + sTmp[1] + sTmp[2] + sTmp[3]) / 4096.f;
    }
}

extern "C" void kernel_launch(void* const* d_in, const int* in_sizes, int n_in,
                              void* d_out, int out_size, void* d_ws, size_t ws_size,
                              hipStream_t stream) {
    const float* x        = (const float*)d_in[0];
    const float* W1       = (const float*)d_in[1];
    const float* b1       = (const float*)d_in[2];
    const float* W2       = (const float*)d_in[3];
    const float* b2       = (const float*)d_in[4];
    const float* Wv       = (const float*)d_in[5];
    const float* bv       = (const float*)d_in[6];
    const float* centers  = (const float*)d_in[7];
    const float* codebook = (const float*)d_in[8];
    const float* Ws1      = (const float*)d_in[9];
    const float* bs1      = (const float*)d_in[10];
    const float* Ws2      = (const float*)d_in[11];
    const float* bs2      = (const float*)d_in[12];
    float* out = (float*)d_out;
    float* ws  = (float*)d_ws;

    float* h1    = ws;                                   // 4096*256
    float* vpart = ws + 4096 * 256;                      // 4*4096*32
    float* vloc  = ws + 4096 * 256 + 4 * 4096 * 32;      // 4096*32
    float* lpart = ws + 4096 * 256 + 5 * 4096 * 32;      // 512

    gemm_bias_gelu<128><<<dim3(4, 128), dim3(256), 0, stream>>>(x, W1, b1, h1);
    gemm2_vproj<<<dim3(4, 128), dim3(256), 0, stream>>>(h1, W2, b2, Wv, vpart);
    vq_chart<<<dim3(512), dim3(256), 0, stream>>>(codebook, centers, bv, vpart,
                                                  Ws1, bs1, Ws2, bs2, out, vloc, lpart);
    finalize2_kernel<<<dim3(512), dim3(256), 0, stream>>>(codebook, vloc, out, lpart);
}

// Round 8
// 65.236 us; speedup vs baseline: 1.0366x; 1.0366x over previous
//
#include <hip/hip_runtime.h>
#include <math.h>

#define NB 4096
#define NIN 128
#define NH 256
#define ND 32
#define NC 8
#define NK 256
#define NHS 16

// output offsets (in floats), concatenated in reference return order
#define OFF_KCHART 0
#define OFF_KCODE  4096
#define OFF_ZN     8192
#define OFF_ZTEX   (OFF_ZN + 4096*32)        // 139264
#define OFF_ROUTER (OFF_ZTEX + 4096*32)      // 270336 (float4-aligned)
#define OFF_ZGEO   (OFF_ROUTER + 4096*8)     // 303104
#define OFF_LOSS   (OFF_ZGEO + 4096*32)      // 434176
#define OFF_IND    (OFF_LOSS + 1)            // 434177 (odd -> scalar access only)
#define OFF_ZNALL  (OFF_IND + 4096*8)        // 466945 (odd -> scalar access only)
#define OFF_CBAR   (OFF_ZNALL + 4096*8*32)   // 1515521 (odd -> scalar)
#define OFF_VLOC   (OFF_CBAR + 4096*32)      // 1646593 (odd -> scalar)

__device__ __forceinline__ float gelu_exact(float x) {
    return x * (erff(x / 1.41421356237309504f) + 1.0f) * 0.5f;
}

// ---------------------------------------------------------------------------
// GEMM (r5-verified): out = gelu(A[M][K] @ W[K][256] + b). 64x64 tile,
// 256 thr, 4x4 micro (R=4: each B b128 feeds 16 FMAs), grid (4,64).
// B in LDS (dbuf, one barrier/tile); A streamed global->regs.
// ---------------------------------------------------------------------------
template<int K>
__global__ __launch_bounds__(256)
void gemm_bias_gelu(const float* __restrict__ A, const float* __restrict__ W,
                    const float* __restrict__ bias, float* __restrict__ out) {
    const int N = 256;
    __shared__ float sB[2][32][68];
    const int t  = threadIdx.x;
    const int n0 = blockIdx.x * 64;
    const int r0 = blockIdx.y * 64;
    const int ty = t >> 4, tx = t & 15;
    const int bk = t >> 4, bc = t & 15;

    float4 bias4 = *(const float4*)(bias + n0 + tx * 4);

    float4 pb0 = *(const float4*)(W + bk * N + n0 + bc * 4);
    float4 pb1 = *(const float4*)(W + (bk + 16) * N + n0 + bc * 4);

    const float* Ab0 = A + (r0 + ty * 4 + 0) * K;
    const float* Ab1 = A + (r0 + ty * 4 + 1) * K;
    const float* Ab2 = A + (r0 + ty * 4 + 2) * K;
    const float* Ab3 = A + (r0 + ty * 4 + 3) * K;
    float ac[4][4], an[4][4];
    {
        float4 c0 = *(const float4*)(Ab0 + 0), c1 = *(const float4*)(Ab1 + 0);
        float4 c2 = *(const float4*)(Ab2 + 0), c3 = *(const float4*)(Ab3 + 0);
        ac[0][0]=c0.x; ac[0][1]=c0.y; ac[0][2]=c0.z; ac[0][3]=c0.w;
        ac[1][0]=c1.x; ac[1][1]=c1.y; ac[1][2]=c1.z; ac[1][3]=c1.w;
        ac[2][0]=c2.x; ac[2][1]=c2.y; ac[2][2]=c2.z; ac[2][3]=c2.w;
        ac[3][0]=c3.x; ac[3][1]=c3.y; ac[3][2]=c3.z; ac[3][3]=c3.w;
        float4 n0v = *(const float4*)(Ab0 + 4), n1v = *(const float4*)(Ab1 + 4);
        float4 n2v = *(const float4*)(Ab2 + 4), n3v = *(const float4*)(Ab3 + 4);
        an[0][0]=n0v.x; an[0][1]=n0v.y; an[0][2]=n0v.z; an[0][3]=n0v.w;
        an[1][0]=n1v.x; an[1][1]=n1v.y; an[1][2]=n1v.z; an[1][3]=n1v.w;
        an[2][0]=n2v.x; an[2][1]=n2v.y; an[2][2]=n2v.z; an[2][3]=n2v.w;
        an[3][0]=n3v.x; an[3][1]=n3v.y; an[3][2]=n3v.z; an[3][3]=n3v.w;
    }

    float acc[4][4];
    #pragma unroll
    for (int i = 0; i < 4; i++)
        #pragma unroll
        for (int j = 0; j < 4; j++) acc[i][j] = 0.f;

    int buf = 0;
    for (int kk = 0; kk < K; kk += 32) {
        *(float4*)(&sB[buf][bk][bc*4])    = pb0;
        *(float4*)(&sB[buf][bk+16][bc*4]) = pb1;
        __syncthreads();
        if (kk + 32 < K) {
            pb0 = *(const float4*)(W + (kk + 32 + bk) * N + n0 + bc * 4);
            pb1 = *(const float4*)(W + (kk + 32 + bk + 16) * N + n0 + bc * 4);
        }
        #pragma unroll
        for (int c = 0; c < 8; c++) {
            int knext = kk + (c + 2) * 4;
            if (knext > K - 4) knext = K - 4;
            float4 p0 = *(const float4*)(Ab0 + knext);
            float4 p1 = *(const float4*)(Ab1 + knext);
            float4 p2 = *(const float4*)(Ab2 + knext);
            float4 p3 = *(const float4*)(Ab3 + knext);
            #pragma unroll
            for (int u = 0; u < 4; u++) {
                float4 bv = *(const float4*)(&sB[buf][c * 4 + u][tx * 4]);
                float bb[4] = {bv.x, bv.y, bv.z, bv.w};
                #pragma unroll
                for (int j = 0; j < 4; j++) {
                    acc[0][j] = fmaf(ac[0][u], bb[j], acc[0][j]);
                    acc[1][j] = fmaf(ac[1][u], bb[j], acc[1][j]);
                    acc[2][j] = fmaf(ac[2][u], bb[j], acc[2][j]);
                    acc[3][j] = fmaf(ac[3][u], bb[j], acc[3][j]);
                }
            }
            #pragma unroll
            for (int u = 0; u < 4; u++) {
                ac[0][u] = an[0][u]; ac[1][u] = an[1][u];
                ac[2][u] = an[2][u]; ac[3][u] = an[3][u];
            }
            an[0][0]=p0.x; an[0][1]=p0.y; an[0][2]=p0.z; an[0][3]=p0.w;
            an[1][0]=p1.x; an[1][1]=p1.y; an[1][2]=p1.z; an[1][3]=p1.w;
            an[2][0]=p2.x; an[2][1]=p2.y; an[2][2]=p2.z; an[2][3]=p2.w;
            an[3][0]=p3.x; an[3][1]=p3.y; an[3][2]=p3.z; an[3][3]=p3.w;
        }
        buf ^= 1;
    }
    float bb4[4] = {bias4.x, bias4.y, bias4.z, bias4.w};
    #pragma unroll
    for (int i = 0; i < 4; i++) {
        int row = r0 + ty * 4 + i;
        float4 o;
        float* op = (float*)&o;
        #pragma unroll
        for (int j = 0; j < 4; j++) op[j] = gelu_exact(acc[i][j] + bb4[j]);
        *(float4*)(out + row * N + n0 + tx * 4) = o;
    }
}

// ---------------------------------------------------------------------------
// router (r6-verified): 8 rows/block, grid 512, one col/thread.
// ---------------------------------------------------------------------------
__global__ __launch_bounds__(256)
void router_kernel(const float* __restrict__ feats, const float* __restrict__ Wv,
                   const float* __restrict__ bv, const float* __restrict__ centers,
                   float* __restrict__ out, float* __restrict__ vloc_ws) {
    __shared__ float sWvT[ND][260];
    __shared__ float sCent[NC * ND];
    __shared__ float sV[8][ND + 2];
    __shared__ float sScore[8][NC];
    __shared__ float sRout[8][NC];
    const int t = threadIdx.x;
    const int row0 = blockIdx.x * 8;
    {
        #pragma unroll
        for (int q = 0; q < 8; q++) {
            int id = t + q * 256;
            int k = id >> 3, c4 = (id & 7) * 4;
            float4 w = ((const float4*)Wv)[id];
            sWvT[c4 + 0][k] = w.x;
            sWvT[c4 + 1][k] = w.y;
            sWvT[c4 + 2][k] = w.z;
            sWvT[c4 + 3][k] = w.w;
        }
        if (t < 64) ((float4*)sCent)[t] = ((const float4*)centers)[t];
    }
    __syncthreads();
    const int r = t >> 5, cp = t & 31;
    const int row = row0 + r;
    float a0 = bv[cp];
    const float4* f4 = (const float4*)(feats + row * NH);
    for (int k4 = 0; k4 < NH / 4; k4++) {
        float4 f = f4[k4];
        float4 w = *(const float4*)(&sWvT[cp][k4 * 4]);
        a0 = fmaf(f.x, w.x, a0);
        a0 = fmaf(f.y, w.y, a0);
        a0 = fmaf(f.z, w.z, a0);
        a0 = fmaf(f.w, w.w, a0);
    }
    sV[r][cp] = a0;
    __syncthreads();
    if (t < 64) {
        int rr = t >> 3, c = t & 7;
        float s = 0.f;
        #pragma unroll
        for (int k = 0; k < ND; k++) s = fmaf(sV[rr][k], sCent[c * ND + k], s);
        sScore[rr][c] = s / 5.65685424949238f;
    }
    __syncthreads();
    if (t < 8) {
        const int rr = t, grow = row0 + rr;
        float sc[NC];
        float m = -3.4e38f; int kmax = 0;
        #pragma unroll
        for (int c = 0; c < NC; c++) {
            float s = sScore[rr][c];
            sc[c] = s;
            if (s > m) { m = s; kmax = c; }
        }
        float ssum = 0.f;
        #pragma unroll
        for (int c = 0; c < NC; c++) { float e = expf(sc[c] - m); sc[c] = e; ssum += e; }
        float inv = 1.f / ssum;
        #pragma unroll
        for (int c = 0; c < NC; c++) {
            float rv = sc[c] * inv;
            sRout[rr][c] = rv;
            out[OFF_ROUTER + grow * NC + c] = rv;
        }
        out[OFF_KCHART + grow] = (float)kmax;
    }
    __syncthreads();
    {
        const int col = cp;
        float cb = 0.f;
        #pragma unroll
        for (int c = 0; c < NC; c++) cb = fmaf(sRout[r][c], sCent[c * ND + col], cb);
        float vl = sV[r][col] - cb;
        out[OFF_CBAR + row * ND + col] = cb;
        out[OFF_VLOC + row * ND + col] = vl;
        vloc_ws[row * ND + col] = vl;
    }
}

// ---------------------------------------------------------------------------
// vq_chart v3: block = 64 rows x 1 chart, grid 512.
// Argmin: 4 rows/thread (r=t&15 owns rows r,r+16,r+32,r+48), g=t>>4 scans
// 16 codes, rotated (j+4g)&15 to break the 4-way sCB bank alias; explicit
// lowest-index tie-guards keep first-occurrence argmin semantics.
// zn MLP: Ws1/Ws2 staged TRANSPOSED and preloaded to regs.
// ---------------------------------------------------------------------------
__global__ __launch_bounds__(256, 2)
void vq_chart(const float* __restrict__ codebook, const float* __restrict__ vloc_ws,
              const float* __restrict__ Ws1, const float* __restrict__ bs1,
              const float* __restrict__ Ws2, const float* __restrict__ bs2,
              float* __restrict__ out, float* __restrict__ loss_partial) {
    __shared__ float sCB[NK][36];
    __shared__ float sEn2[NK];
    __shared__ float sV[64][36];
    __shared__ float sBest[16][64];
    __shared__ int   sBidx[16][64];
    __shared__ int   sSel[64];
    __shared__ float sRoutv[64];
    __shared__ float sPscale[64];
    __shared__ float sLossArr[64];
    __shared__ float sWs1T[NHS][36];   // [i][k] = Ws1[k][i]
    __shared__ float sWs2T[ND][20];    // [c][k] = Ws2[k][c]
    __shared__ float sbs1[NHS], sbs2v[ND];
    const int t = threadIdx.x;
    const int c = blockIdx.x & 7;
    const int row0 = (blockIdx.x >> 3) * 64;

    {
        const float4* src = (const float4*)(codebook + c * NK * ND);
        #pragma unroll
        for (int q = 0; q < 8; q++) {
            int id = t + q * 256;
            int code = id >> 3, kq = (id & 7) * 4;
            *(float4*)(&sCB[code][kq]) = src[id];
        }
        #pragma unroll
        for (int q = 0; q < 2; q++) {
            int id = t + q * 256;
            int rr = id >> 3, kq = (id & 7) * 4;
            *(float4*)(&sV[rr][kq]) = ((const float4*)(vloc_ws + row0 * ND))[id];
        }
    }
    if (t < 128) {          // Ws1 (32x16): transpose into sWs1T[i][k]
        float4 w = ((const float4*)Ws1)[t];
        int k = t >> 2, o = (t & 3) * 4;
        sWs1T[o+0][k] = w.x; sWs1T[o+1][k] = w.y;
        sWs1T[o+2][k] = w.z; sWs1T[o+3][k] = w.w;
    } else {                // Ws2 (16x32): transpose into sWs2T[c][k]
        int u = t - 128;
        float4 w = ((const float4*)Ws2)[u];
        int k = u >> 3, o = (u & 7) * 4;
        sWs2T[o+0][k] = w.x; sWs2T[o+1][k] = w.y;
        sWs2T[o+2][k] = w.z; sWs2T[o+3][k] = w.w;
    }
    if (t < NHS) sbs1[t] = bs1[t];
    else if (t < NHS + ND) sbs2v[t - NHS] = bs2[t - NHS];
    if (t < 64) sRoutv[t] = out[OFF_ROUTER + (row0 + t) * NC + c];
    __syncthreads();
    // per-code squared norms
    {
        float s = 0.f;
        #pragma unroll
        for (int q = 0; q < 8; q++) {
            float4 e = *(const float4*)(&sCB[t][q * 4]);
            s = fmaf(e.x, e.x, s); s = fmaf(e.y, e.y, s);
            s = fmaf(e.z, e.z, s); s = fmaf(e.w, e.w, s);
        }
        sEn2[t] = s;
    }
    __syncthreads();

    // ---- argmin: 4 rows per thread ----
    {
        const int r = t & 15, g = t >> 4;
        float vl[4][ND];
        #pragma unroll
        for (int u = 0; u < 4; u++) {
            #pragma unroll
            for (int q = 0; q < 8; q++) {
                float4 a = *(const float4*)(&sV[r + u * 16][q * 4]);
                vl[u][q*4] = a.x; vl[u][q*4+1] = a.y;
                vl[u][q*4+2] = a.z; vl[u][q*4+3] = a.w;
            }
        }
        float best[4] = {3.4e38f, 3.4e38f, 3.4e38f, 3.4e38f};
        int bi[4] = {0, 0, 0, 0};
        for (int j = 0; j < 16; j++) {
            const int code = g * 16 + ((j + g * 4) & 15);   // rotation: 2-way banks
            float dot[4] = {0.f, 0.f, 0.f, 0.f};
            #pragma unroll
            for (int q = 0; q < 8; q++) {
                float4 e = *(const float4*)(&sCB[code][q * 4]);
                #pragma unroll
                for (int u = 0; u < 4; u++) {
                    dot[u] = fmaf(vl[u][q*4+0], e.x, dot[u]);
                    dot[u] = fmaf(vl[u][q*4+1], e.y, dot[u]);
                    dot[u] = fmaf(vl[u][q*4+2], e.z, dot[u]);
                    dot[u] = fmaf(vl[u][q*4+3], e.w, dot[u]);
                }
            }
            const float en2 = sEn2[code];
            #pragma unroll
            for (int u = 0; u < 4; u++) {
                float d = en2 - 2.f * dot[u];
                if (d < best[u] || (d == best[u] && code < bi[u])) {
                    best[u] = d; bi[u] = code;
                }
            }
        }
        #pragma unroll
        for (int u = 0; u < 4; u++) {
            sBest[g][r + u * 16] = best[u];
            sBidx[g][r + u * 16] = bi[u];
        }
    }
    __syncthreads();
    if (t < 64) {
        float bb = sBest[0][t]; int ii = sBidx[0][t];
        #pragma unroll
        for (int gg = 1; gg < 16; gg++) {
            float v = sBest[gg][t]; int id = sBidx[gg][t];
            if (v < bb || (v == bb && id < ii)) { bb = v; ii = id; }
        }
        sSel[t] = ii;
        out[OFF_IND + (row0 + t) * NC + c] = (float)ii;
        float vn2 = 0.f;
        #pragma unroll
        for (int k = 0; k < ND; k++) { float v = sV[t][k]; vn2 = fmaf(v, v, vn2); }
        float norm = fmaxf(sqrtf(vn2), 1e-6f);
        sPscale[t] = fminf(0.99f / norm, 1.0f);
    }
    __syncthreads();

    // ---- zn MLP + loss, 4 passes of 16 rows; Ws in registers ----
    const int i = t & 15, r16 = t >> 4;
    const float b1r = sbs1[i];
    const float bo0 = sbs2v[2*i], bo1 = sbs2v[2*i+1];
    float w1c[ND], w2a[NHS], w2b[NHS];
    #pragma unroll
    for (int q = 0; q < 8; q++) {
        float4 w = *(const float4*)(&sWs1T[i][q * 4]);
        w1c[q*4] = w.x; w1c[q*4+1] = w.y; w1c[q*4+2] = w.z; w1c[q*4+3] = w.w;
    }
    #pragma unroll
    for (int q = 0; q < 4; q++) {
        float4 a = *(const float4*)(&sWs2T[2*i][q * 4]);
        w2a[q*4] = a.x; w2a[q*4+1] = a.y; w2a[q*4+2] = a.z; w2a[q*4+3] = a.w;
        float4 b = *(const float4*)(&sWs2T[2*i+1][q * 4]);
        w2b[q*4] = b.x; w2b[q*4+1] = b.y; w2b[q*4+2] = b.z; w2b[q*4+3] = b.w;
    }
    #pragma unroll
    for (int pass = 0; pass < 4; pass++) {
        const int lrow = pass * 16 + r16;
        const int grow = row0 + lrow;
        const int sel = sSel[lrow];
        const float rc = sRoutv[lrow];
        const float ps = sPscale[lrow];
        float dta[ND];
        #pragma unroll
        for (int q = 0; q < 8; q++) {
            float4 vv = *(const float4*)(&sV[lrow][q * 4]);
            float4 ee = *(const float4*)(&sCB[sel][q * 4]);
            dta[q*4+0] = vv.x - ee.x; dta[q*4+1] = vv.y - ee.y;
            dta[q*4+2] = vv.z - ee.z; dta[q*4+3] = vv.w - ee.w;
        }
        float acc1 = b1r;
        #pragma unroll
        for (int k = 0; k < ND; k++) acc1 = fmaf(dta[k], w1c[k], acc1);
        float h = gelu_exact(acc1);
        float a0 = bo0, a1 = bo1;
        #pragma unroll
        for (int k = 0; k < NHS; k++) {
            float s1k = __shfl(h, k, 16);
            a0 = fmaf(s1k, w2a[k], a0);
            a1 = fmaf(s1k, w2b[k], a1);
        }
        out[OFF_ZNALL + (grow * NC + c) * ND + 2*i]     = a0;
        out[OFF_ZNALL + (grow * NC + c) * ND + 2*i + 1] = a1;
        const float e0 = sCB[sel][2*i], e1 = sCB[sel][2*i+1];
        float yp0 = sV[lrow][2*i] * ps, yp1 = sV[lrow][2*i+1] * ps;
        float d0 = e0 - yp0, d1 = e1 - yp1;
        float sq = fmaf(d0, d0, d1 * d1);
        float xn = fmaf(e0, e0, e1 * e1);
        float yn = fmaf(yp0, yp0, yp1 * yp1);
        #pragma unroll
        for (int m = 1; m < 16; m <<= 1) {
            sq += __shfl_xor(sq, m, 16);
            xn += __shfl_xor(xn, m, 16);
            yn += __shfl_xor(yn, m, 16);
        }
        if (i == 0) {
            float denom = fmaxf((1.f - xn) * (1.f - yn), 1e-6f);
            float arg = fmaxf(1.f + 2.f * sq / denom, 1.f + 1e-6f);
            float dd = acoshf(arg);
            sLossArr[lrow] = dd * dd * rc;
        }
    }
    __syncthreads();
    if (t < 64) {
        float v = sLossArr[t];
        #pragma unroll
        for (int off = 32; off > 0; off >>= 1) v += __shfl_down(v, off, 64);
        if (t == 0) loss_partial[blockIdx.x] = v;
    }
}

// ---------------------------------------------------------------------------
// finalize (r6-verified): one col/thread, grid 512 + loss reduce in block 0.
// ---------------------------------------------------------------------------
__global__ __launch_bounds__(256)
void finalize2_kernel(const float* __restrict__ codebook, const float* __restrict__ vloc_ws,
                      float* __restrict__ out, const float* __restrict__ partials) {
    const int gid = blockIdx.x * 256 + threadIdx.x;
    const int row = gid >> 5;
    const int col = gid & 31;
    float rout[NC]; int ind[NC];
    #pragma unroll
    for (int cc = 0; cc < NC; cc++) {
        rout[cc] = out[OFF_ROUTER + row * NC + cc];
        ind[cc]  = (int)out[OFF_IND + row * NC + cc];
    }
    float zn = 0.f, zq = 0.f;
    #pragma unroll
    for (int cc = 0; cc < NC; cc++) {
        const float rcc = rout[cc];
        zn = fmaf(out[OFF_ZNALL + (row * NC + cc) * ND + col], rcc, zn);
        zq = fmaf(codebook[(cc * NK + ind[cc]) * ND + col], rcc, zq);
    }
    const float vl = vloc_ws[row * ND + col];
    const float cb = out[OFF_CBAR + row * ND + col];
    out[OFF_ZN   + row * ND + col] = zn;
    out[OFF_ZTEX + row * ND + col] = vl - zq - zn;
    out[OFF_ZGEO + row * ND + col] = cb + zq + zn;
    if (col == 0) {
        int kc = (int)out[OFF_KCHART + row];
        out[OFF_KCODE + row] = out[OFF_IND + row * NC + kc];
    }
    if (blockIdx.x == 0) {
        __shared__ float sTmp[4];
        const int t = threadIdx.x;
        float v = partials[t] + partials[t + 256];
        #pragma unroll
        for (int off = 32; off > 0; off >>= 1) v += __shfl_down(v, off, 64);
        if ((t & 63) == 0) sTmp[t >> 6] = v;
        __syncthreads();
        if (t == 0) out[OFF_LOSS] = 1.25f * (sTmp[0] + sTmp[1] + sTmp[2] + sTmp[3]) / 4096.f;
    }
}

extern "C" void kernel_launch(void* const* d_in, const int* in_sizes, int n_in,
                              void* d_out, int out_size, void* d_ws, size_t ws_size,
                              hipStream_t stream) {
    const float* x        = (const float*)d_in[0];
    const float* W1       = (const float*)d_in[1];
    const float* b1       = (const float*)d_in[2];
    const float* W2       = (const float*)d_in[3];
    const float* b2       = (const float*)d_in[4];
    const float* Wv       = (const float*)d_in[5];
    const float* bv       = (const float*)d_in[6];
    const float* centers  = (const float*)d_in[7];
    const float* codebook = (const float*)d_in[8];
    const float* Ws1      = (const float*)d_in[9];
    const float* bs1      = (const float*)d_in[10];
    const float* Ws2      = (const float*)d_in[11];
    const float* bs2      = (const float*)d_in[12];
    float* out = (float*)d_out;
    float* ws  = (float*)d_ws;

    float* h1       = ws;                                // 4096*256
    float* feats    = ws + 4096 * 256;                   // 4096*256
    float* vloc     = ws + 2 * 4096 * 256;               // 4096*32
    float* partials = ws + 2 * 4096 * 256 + 4096 * 32;   // 512

    gemm_bias_gelu<128><<<dim3(4, 64), dim3(256), 0, stream>>>(x, W1, b1, h1);
    gemm_bias_gelu<256><<<dim3(4, 64), dim3(256), 0, stream>>>(h1, W2, b2, feats);
    router_kernel<<<dim3(512), dim3(256), 0, stream>>>(feats, Wv, bv, centers, out, vloc);
    vq_chart<<<dim3(512), dim3(256), 0, stream>>>(codebook, vloc, Ws1, bs1, Ws2, bs2, out, partials);
    finalize2_kernel<<<dim3(512), dim3(256), 0, stream>>>(codebook, vloc, out, partials);
}

// Round 9
// 60.442 us; speedup vs baseline: 1.1188x; 1.0793x over previous
//
#include <hip/hip_runtime.h>
#include <math.h>

#define NB 4096
#define NIN 128
#define NH 256
#define ND 32
#define NC 8
#define NK 256
#define NHS 16

// output offsets (in floats), concatenated in reference return order
#define OFF_KCHART 0
#define OFF_KCODE  4096
#define OFF_ZN     8192
#define OFF_ZTEX   (OFF_ZN + 4096*32)        // 139264
#define OFF_ROUTER (OFF_ZTEX + 4096*32)      // 270336 (float4-aligned)
#define OFF_ZGEO   (OFF_ROUTER + 4096*8)     // 303104
#define OFF_LOSS   (OFF_ZGEO + 4096*32)      // 434176
#define OFF_IND    (OFF_LOSS + 1)            // 434177 (odd -> scalar access only)
#define OFF_ZNALL  (OFF_IND + 4096*8)        // 466945 (odd -> scalar access only)
#define OFF_CBAR   (OFF_ZNALL + 4096*8*32)   // 1515521 (odd -> scalar)
#define OFF_VLOC   (OFF_CBAR + 4096*32)      // 1646593 (odd -> scalar)

__device__ __forceinline__ float gelu_exact(float x) {
    return x * (erff(x / 1.41421356237309504f) + 1.0f) * 0.5f;
}

// ---------------------------------------------------------------------------
// GEMM (r6-verified, 60.0us config): 32x64 tile, 2x4 micro, grid (4,128)
// = 512 blocks = 2 blocks/CU. B in LDS (dbuf, one barrier/tile); A streamed
// global->regs. TLP > LDS-inst-count at this size (r5/r8 evidence).
// ---------------------------------------------------------------------------
template<int K>
__global__ __launch_bounds__(256)
void gemm_bias_gelu(const float* __restrict__ A, const float* __restrict__ W,
                    const float* __restrict__ bias, float* __restrict__ out) {
    const int N = 256;
    __shared__ float sB[2][32][68];
    const int t  = threadIdx.x;
    const int n0 = blockIdx.x * 64;
    const int r0 = blockIdx.y * 32;
    const int ty = t >> 4, tx = t & 15;
    const int bk = t >> 4, bc = t & 15;

    float4 bias4 = *(const float4*)(bias + n0 + tx * 4);

    float4 pb0 = *(const float4*)(W + bk * N + n0 + bc * 4);
    float4 pb1 = *(const float4*)(W + (bk + 16) * N + n0 + bc * 4);

    const float* Ab0 = A + (r0 + ty * 2 + 0) * K;
    const float* Ab1 = A + (r0 + ty * 2 + 1) * K;
    float ac[2][4], an[2][4];
    {
        float4 c0 = *(const float4*)(Ab0 + 0), c1 = *(const float4*)(Ab1 + 0);
        ac[0][0]=c0.x; ac[0][1]=c0.y; ac[0][2]=c0.z; ac[0][3]=c0.w;
        ac[1][0]=c1.x; ac[1][1]=c1.y; ac[1][2]=c1.z; ac[1][3]=c1.w;
        float4 d0 = *(const float4*)(Ab0 + 4), d1 = *(const float4*)(Ab1 + 4);
        an[0][0]=d0.x; an[0][1]=d0.y; an[0][2]=d0.z; an[0][3]=d0.w;
        an[1][0]=d1.x; an[1][1]=d1.y; an[1][2]=d1.z; an[1][3]=d1.w;
    }

    float acc[2][4];
    #pragma unroll
    for (int i = 0; i < 2; i++)
        #pragma unroll
        for (int j = 0; j < 4; j++) acc[i][j] = 0.f;

    int buf = 0;
    for (int kk = 0; kk < K; kk += 32) {
        *(float4*)(&sB[buf][bk][bc*4])    = pb0;
        *(float4*)(&sB[buf][bk+16][bc*4]) = pb1;
        __syncthreads();
        if (kk + 32 < K) {
            pb0 = *(const float4*)(W + (kk + 32 + bk) * N + n0 + bc * 4);
            pb1 = *(const float4*)(W + (kk + 32 + bk + 16) * N + n0 + bc * 4);
        }
        #pragma unroll
        for (int c = 0; c < 8; c++) {
            int knext = kk + (c + 2) * 4;
            if (knext > K - 4) knext = K - 4;
            float4 p0 = *(const float4*)(Ab0 + knext);
            float4 p1 = *(const float4*)(Ab1 + knext);
            #pragma unroll
            for (int u = 0; u < 4; u++) {
                float4 bv = *(const float4*)(&sB[buf][c * 4 + u][tx * 4]);
                float bb[4] = {bv.x, bv.y, bv.z, bv.w};
                #pragma unroll
                for (int j = 0; j < 4; j++) {
                    acc[0][j] = fmaf(ac[0][u], bb[j], acc[0][j]);
                    acc[1][j] = fmaf(ac[1][u], bb[j], acc[1][j]);
                }
            }
            #pragma unroll
            for (int u = 0; u < 4; u++) { ac[0][u] = an[0][u]; ac[1][u] = an[1][u]; }
            an[0][0]=p0.x; an[0][1]=p0.y; an[0][2]=p0.z; an[0][3]=p0.w;
            an[1][0]=p1.x; an[1][1]=p1.y; an[1][2]=p1.z; an[1][3]=p1.w;
        }
        buf ^= 1;
    }
    float bb4[4] = {bias4.x, bias4.y, bias4.z, bias4.w};
    #pragma unroll
    for (int i = 0; i < 2; i++) {
        int row = r0 + ty * 2 + i;
        float4 o;
        float* op = (float*)&o;
        #pragma unroll
        for (int j = 0; j < 4; j++) op[j] = gelu_exact(acc[i][j] + bb4[j]);
        *(float4*)(out + row * N + n0 + tx * 4) = o;
    }
}

// ---------------------------------------------------------------------------
// router v3: 8 rows/block, grid 512, one col/thread. Wv staged transposed
// with row stride 272 floats + XOR swizzle of 16B block index (kb ^= cp&7)
// -> 2-way bank aliasing (free, m136) instead of r6's 4-way conflict.
// ---------------------------------------------------------------------------
__global__ __launch_bounds__(256)
void router_kernel(const float* __restrict__ feats, const float* __restrict__ Wv,
                   const float* __restrict__ bv, const float* __restrict__ centers,
                   float* __restrict__ out, float* __restrict__ vloc_ws) {
    __shared__ float sWv[32 * 272];    // [col][k] swizzled, 34.8 KB
    __shared__ float sCent[NC * ND];
    __shared__ float sV[8][ND + 2];
    __shared__ float sScore[8][NC];
    __shared__ float sRout[8][NC];
    const int t = threadIdx.x;
    const int row0 = blockIdx.x * 8;
    {
        #pragma unroll
        for (int q = 0; q < 8; q++) {
            int id = t + q * 256;
            int k = id >> 3, c4 = (id & 7) * 4;
            int kb = k >> 2, kr = k & 3;
            float4 w = ((const float4*)Wv)[id];
            sWv[(c4+0) * 272 + ((kb ^ ((c4+0) & 7)) << 2) + kr] = w.x;
            sWv[(c4+1) * 272 + ((kb ^ ((c4+1) & 7)) << 2) + kr] = w.y;
            sWv[(c4+2) * 272 + ((kb ^ ((c4+2) & 7)) << 2) + kr] = w.z;
            sWv[(c4+3) * 272 + ((kb ^ ((c4+3) & 7)) << 2) + kr] = w.w;
        }
        if (t < 64) ((float4*)sCent)[t] = ((const float4*)centers)[t];
    }
    __syncthreads();
    const int r = t >> 5, cp = t & 31;
    const int row = row0 + r;
    const int cbase = cp * 272, cxor = cp & 7;
    float a0 = bv[cp];
    const float4* f4 = (const float4*)(feats + row * NH);
    for (int k4 = 0; k4 < NH / 4; k4++) {
        float4 f = f4[k4];
        float4 w = *(const float4*)(&sWv[cbase + ((k4 ^ cxor) << 2)]);
        a0 = fmaf(f.x, w.x, a0);
        a0 = fmaf(f.y, w.y, a0);
        a0 = fmaf(f.z, w.z, a0);
        a0 = fmaf(f.w, w.w, a0);
    }
    sV[r][cp] = a0;
    __syncthreads();
    if (t < 64) {
        int rr = t >> 3, c = t & 7;
        float s = 0.f;
        #pragma unroll
        for (int k = 0; k < ND; k++) s = fmaf(sV[rr][k], sCent[c * ND + k], s);
        sScore[rr][c] = s / 5.65685424949238f;
    }
    __syncthreads();
    if (t < 8) {
        const int rr = t, grow = row0 + rr;
        float sc[NC];
        float m = -3.4e38f; int kmax = 0;
        #pragma unroll
        for (int c = 0; c < NC; c++) {
            float s = sScore[rr][c];
            sc[c] = s;
            if (s > m) { m = s; kmax = c; }
        }
        float ssum = 0.f;
        #pragma unroll
        for (int c = 0; c < NC; c++) { float e = expf(sc[c] - m); sc[c] = e; ssum += e; }
        float inv = 1.f / ssum;
        #pragma unroll
        for (int c = 0; c < NC; c++) {
            float rv = sc[c] * inv;
            sRout[rr][c] = rv;
            out[OFF_ROUTER + grow * NC + c] = rv;
        }
        out[OFF_KCHART + grow] = (float)kmax;
    }
    __syncthreads();
    {
        const int col = cp;
        float cb = 0.f;
        #pragma unroll
        for (int c = 0; c < NC; c++) cb = fmaf(sRout[r][c], sCent[c * ND + col], cb);
        float vl = sV[r][col] - cb;
        out[OFF_CBAR + row * ND + col] = cb;
        out[OFF_VLOC + row * ND + col] = vl;
        vloc_ws[row * ND + col] = vl;
    }
}

// ---------------------------------------------------------------------------
// vq_chart v3 (r8-verified-correct): block = 64 rows x 1 chart, grid 512.
// Argmin: 4 rows/thread (16:1 FMA:LDS ratio), code rotation for 2-way banks,
// tie-guards preserve first-occurrence argmin. zn MLP: Ws in registers.
// ---------------------------------------------------------------------------
__global__ __launch_bounds__(256, 2)
void vq_chart(const float* __restrict__ codebook, const float* __restrict__ vloc_ws,
              const float* __restrict__ Ws1, const float* __restrict__ bs1,
              const float* __restrict__ Ws2, const float* __restrict__ bs2,
              float* __restrict__ out, float* __restrict__ loss_partial) {
    __shared__ float sCB[NK][36];
    __shared__ float sEn2[NK];
    __shared__ float sV[64][36];
    __shared__ float sBest[16][64];
    __shared__ int   sBidx[16][64];
    __shared__ int   sSel[64];
    __shared__ float sRoutv[64];
    __shared__ float sPscale[64];
    __shared__ float sLossArr[64];
    __shared__ float sWs1T[NHS][36];   // [i][k] = Ws1[k][i]
    __shared__ float sWs2T[ND][20];    // [c][k] = Ws2[k][c]
    __shared__ float sbs1[NHS], sbs2v[ND];
    const int t = threadIdx.x;
    const int c = blockIdx.x & 7;
    const int row0 = (blockIdx.x >> 3) * 64;

    {
        const float4* src = (const float4*)(codebook + c * NK * ND);
        #pragma unroll
        for (int q = 0; q < 8; q++) {
            int id = t + q * 256;
            int code = id >> 3, kq = (id & 7) * 4;
            *(float4*)(&sCB[code][kq]) = src[id];
        }
        #pragma unroll
        for (int q = 0; q < 2; q++) {
            int id = t + q * 256;
            int rr = id >> 3, kq = (id & 7) * 4;
            *(float4*)(&sV[rr][kq]) = ((const float4*)(vloc_ws + row0 * ND))[id];
        }
    }
    if (t < 128) {          // Ws1 (32x16): transpose into sWs1T[i][k]
        float4 w = ((const float4*)Ws1)[t];
        int k = t >> 2, o = (t & 3) * 4;
        sWs1T[o+0][k] = w.x; sWs1T[o+1][k] = w.y;
        sWs1T[o+2][k] = w.z; sWs1T[o+3][k] = w.w;
    } else {                // Ws2 (16x32): transpose into sWs2T[c][k]
        int u = t - 128;
        float4 w = ((const float4*)Ws2)[u];
        int k = u >> 3, o = (u & 7) * 4;
        sWs2T[o+0][k] = w.x; sWs2T[o+1][k] = w.y;
        sWs2T[o+2][k] = w.z; sWs2T[o+3][k] = w.w;
    }
    if (t < NHS) sbs1[t] = bs1[t];
    else if (t < NHS + ND) sbs2v[t - NHS] = bs2[t - NHS];
    if (t < 64) sRoutv[t] = out[OFF_ROUTER + (row0 + t) * NC + c];
    __syncthreads();
    // per-code squared norms
    {
        float s = 0.f;
        #pragma unroll
        for (int q = 0; q < 8; q++) {
            float4 e = *(const float4*)(&sCB[t][q * 4]);
            s = fmaf(e.x, e.x, s); s = fmaf(e.y, e.y, s);
            s = fmaf(e.z, e.z, s); s = fmaf(e.w, e.w, s);
        }
        sEn2[t] = s;
    }
    __syncthreads();

    // ---- argmin: 4 rows per thread ----
    {
        const int r = t & 15, g = t >> 4;
        float vl[4][ND];
        #pragma unroll
        for (int u = 0; u < 4; u++) {
            #pragma unroll
            for (int q = 0; q < 8; q++) {
                float4 a = *(const float4*)(&sV[r + u * 16][q * 4]);
                vl[u][q*4] = a.x; vl[u][q*4+1] = a.y;
                vl[u][q*4+2] = a.z; vl[u][q*4+3] = a.w;
            }
        }
        float best[4] = {3.4e38f, 3.4e38f, 3.4e38f, 3.4e38f};
        int bi[4] = {0, 0, 0, 0};
        for (int j = 0; j < 16; j++) {
            const int code = g * 16 + ((j + g * 4) & 15);   // rotation: 2-way banks
            float dot[4] = {0.f, 0.f, 0.f, 0.f};
            #pragma unroll
            for (int q = 0; q < 8; q++) {
                float4 e = *(const float4*)(&sCB[code][q * 4]);
                #pragma unroll
                for (int u = 0; u < 4; u++) {
                    dot[u] = fmaf(vl[u][q*4+0], e.x, dot[u]);
                    dot[u] = fmaf(vl[u][q*4+1], e.y, dot[u]);
                    dot[u] = fmaf(vl[u][q*4+2], e.z, dot[u]);
                    dot[u] = fmaf(vl[u][q*4+3], e.w, dot[u]);
                }
            }
            const float en2 = sEn2[code];
            #pragma unroll
            for (int u = 0; u < 4; u++) {
                float d = en2 - 2.f * dot[u];
                if (d < best[u] || (d == best[u] && code < bi[u])) {
                    best[u] = d; bi[u] = code;
                }
            }
        }
        #pragma unroll
        for (int u = 0; u < 4; u++) {
            sBest[g][r + u * 16] = best[u];
            sBidx[g][r + u * 16] = bi[u];
        }
    }
    __syncthreads();
    if (t < 64) {
        float bb = sBest[0][t]; int ii = sBidx[0][t];
        #pragma unroll
        for (int gg = 1; gg < 16; gg++) {
            float v = sBest[gg][t]; int id = sBidx[gg][t];
            if (v < bb || (v == bb && id < ii)) { bb = v; ii = id; }
        }
        sSel[t] = ii;
        out[OFF_IND + (row0 + t) * NC + c] = (float)ii;
        float vn2 = 0.f;
        #pragma unroll
        for (int k = 0; k < ND; k++) { float v = sV[t][k]; vn2 = fmaf(v, v, vn2); }
        float norm = fmaxf(sqrtf(vn2), 1e-6f);
        sPscale[t] = fminf(0.99f / norm, 1.0f);
    }
    __syncthreads();

    // ---- zn MLP + loss, 4 passes of 16 rows; Ws in registers ----
    const int i = t & 15, r16 = t >> 4;
    const float b1r = sbs1[i];
    const float bo0 = sbs2v[2*i], bo1 = sbs2v[2*i+1];
    float w1c[ND], w2a[NHS], w2b[NHS];
    #pragma unroll
    for (int q = 0; q < 8; q++) {
        float4 w = *(const float4*)(&sWs1T[i][q * 4]);
        w1c[q*4] = w.x; w1c[q*4+1] = w.y; w1c[q*4+2] = w.z; w1c[q*4+3] = w.w;
    }
    #pragma unroll
    for (int q = 0; q < 4; q++) {
        float4 a = *(const float4*)(&sWs2T[2*i][q * 4]);
        w2a[q*4] = a.x; w2a[q*4+1] = a.y; w2a[q*4+2] = a.z; w2a[q*4+3] = a.w;
        float4 b = *(const float4*)(&sWs2T[2*i+1][q * 4]);
        w2b[q*4] = b.x; w2b[q*4+1] = b.y; w2b[q*4+2] = b.z; w2b[q*4+3] = b.w;
    }
    #pragma unroll
    for (int pass = 0; pass < 4; pass++) {
        const int lrow = pass * 16 + r16;
        const int grow = row0 + lrow;
        const int sel = sSel[lrow];
        const float rc = sRoutv[lrow];
        const float ps = sPscale[lrow];
        float dta[ND];
        #pragma unroll
        for (int q = 0; q < 8; q++) {
            float4 vv = *(const float4*)(&sV[lrow][q * 4]);
            float4 ee = *(const float4*)(&sCB[sel][q * 4]);
            dta[q*4+0] = vv.x - ee.x; dta[q*4+1] = vv.y - ee.y;
            dta[q*4+2] = vv.z - ee.z; dta[q*4+3] = vv.w - ee.w;
        }
        float acc1 = b1r;
        #pragma unroll
        for (int k = 0; k < ND; k++) acc1 = fmaf(dta[k], w1c[k], acc1);
        float h = gelu_exact(acc1);
        float a0 = bo0, a1 = bo1;
        #pragma unroll
        for (int k = 0; k < NHS; k++) {
            float s1k = __shfl(h, k, 16);
            a0 = fmaf(s1k, w2a[k], a0);
            a1 = fmaf(s1k, w2b[k], a1);
        }
        out[OFF_ZNALL + (grow * NC + c) * ND + 2*i]     = a0;
        out[OFF_ZNALL + (grow * NC + c) * ND + 2*i + 1] = a1;
        const float e0 = sCB[sel][2*i], e1 = sCB[sel][2*i+1];
        float yp0 = sV[lrow][2*i] * ps, yp1 = sV[lrow][2*i+1] * ps;
        float d0 = e0 - yp0, d1 = e1 - yp1;
        float sq = fmaf(d0, d0, d1 * d1);
        float xn = fmaf(e0, e0, e1 * e1);
        float yn = fmaf(yp0, yp0, yp1 * yp1);
        #pragma unroll
        for (int m = 1; m < 16; m <<= 1) {
            sq += __shfl_xor(sq, m, 16);
            xn += __shfl_xor(xn, m, 16);
            yn += __shfl_xor(yn, m, 16);
        }
        if (i == 0) {
            float denom = fmaxf((1.f - xn) * (1.f - yn), 1e-6f);
            float arg = fmaxf(1.f + 2.f * sq / denom, 1.f + 1e-6f);
            float dd = acoshf(arg);
            sLossArr[lrow] = dd * dd * rc;
        }
    }
    __syncthreads();
    if (t < 64) {
        float v = sLossArr[t];
        #pragma unroll
        for (int off = 32; off > 0; off >>= 1) v += __shfl_down(v, off, 64);
        if (t == 0) loss_partial[blockIdx.x] = v;
    }
}

// ---------------------------------------------------------------------------
// finalize (r6-verified): one col/thread, grid 512 + loss reduce in block 0.
// ---------------------------------------------------------------------------
__global__ __launch_bounds__(256)
void finalize2_kernel(const float* __restrict__ codebook, const float* __restrict__ vloc_ws,
                      float* __restrict__ out, const float* __restrict__ partials) {
    const int gid = blockIdx.x * 256 + threadIdx.x;
    const int row = gid >> 5;
    const int col = gid & 31;
    float rout[NC]; int ind[NC];
    #pragma unroll
    for (int cc = 0; cc < NC; cc++) {
        rout[cc] = out[OFF_ROUTER + row * NC + cc];
        ind[cc]  = (int)out[OFF_IND + row * NC + cc];
    }
    float zn = 0.f, zq = 0.f;
    #pragma unroll
    for (int cc = 0; cc < NC; cc++) {
        const float rcc = rout[cc];
        zn = fmaf(out[OFF_ZNALL + (row * NC + cc) * ND + col], rcc, zn);
        zq = fmaf(codebook[(cc * NK + ind[cc]) * ND + col], rcc, zq);
    }
    const float vl = vloc_ws[row * ND + col];
    const float cb = out[OFF_CBAR + row * ND + col];
    out[OFF_ZN   + row * ND + col] = zn;
    out[OFF_ZTEX + row * ND + col] = vl - zq - zn;
    out[OFF_ZGEO + row * ND + col] = cb + zq + zn;
    if (col == 0) {
        int kc = (int)out[OFF_KCHART + row];
        out[OFF_KCODE + row] = out[OFF_IND + row * NC + kc];
    }
    if (blockIdx.x == 0) {
        __shared__ float sTmp[4];
        const int t = threadIdx.x;
        float v = partials[t] + partials[t + 256];
        #pragma unroll
        for (int off = 32; off > 0; off >>= 1) v += __shfl_down(v, off, 64);
        if ((t & 63) == 0) sTmp[t >> 6] = v;
        __syncthreads();
        if (t == 0) out[OFF_LOSS] = 1.25f * (sTmp[0] + sTmp[1] + sTmp[2] + sTmp[3]) / 4096.f;
    }
}

extern "C" void kernel_launch(void* const* d_in, const int* in_sizes, int n_in,
                              void* d_out, int out_size, void* d_ws, size_t ws_size,
                              hipStream_t stream) {
    const float* x        = (const float*)d_in[0];
    const float* W1       = (const float*)d_in[1];
    const float* b1       = (const float*)d_in[2];
    const float* W2       = (const float*)d_in[3];
    const float* b2       = (const float*)d_in[4];
    const float* Wv       = (const float*)d_in[5];
    const float* bv       = (const float*)d_in[6];
    const float* centers  = (const float*)d_in[7];
    const float* codebook = (const float*)d_in[8];
    const float* Ws1      = (const float*)d_in[9];
    const float* bs1      = (const float*)d_in[10];
    const float* Ws2      = (const float*)d_in[11];
    const float* bs2      = (const float*)d_in[12];
    float* out = (float*)d_out;
    float* ws  = (float*)d_ws;

    float* h1       = ws;                                // 4096*256
    float* feats    = ws + 4096 * 256;                   // 4096*256
    float* vloc     = ws + 2 * 4096 * 256;               // 4096*32
    float* partials = ws + 2 * 4096 * 256 + 4096 * 32;   // 512

    gemm_bias_gelu<128><<<dim3(4, 128), dim3(256), 0, stream>>>(x, W1, b1, h1);
    gemm_bias_gelu<256><<<dim3(4, 128), dim3(256), 0, stream>>>(h1, W2, b2, feats);
    router_kernel<<<dim3(512), dim3(256), 0, stream>>>(feats, Wv, bv, centers, out, vloc);
    vq_chart<<<dim3(512), dim3(256), 0, stream>>>(codebook, vloc, Ws1, bs1, Ws2, bs2, out, partials);
    finalize2_kernel<<<dim3(512), dim3(256), 0, stream>>>(codebook, vloc, out, partials);
}